// Round 1
// baseline (2714.524 us; speedup 1.0000x reference)
//
#include <hip/hip_runtime.h>
#include <hip/hip_bf16.h>
#include <math.h>

#define EPS 1e-5f

// ---------------------------------------------------------------------------
// Generic direct convolution: NCHW in, OIHW weights, optional post-bias ReLU.
// out(n,co,oh,ow) = sum_{ci,kh,kw} in(n,ci,oh*s-p+kh, ow*s-p+kw) * w(co,ci,kh,kw) + b(co)
// ---------------------------------------------------------------------------
__global__ void conv_kernel(const float* __restrict__ in, const float* __restrict__ w,
                            const float* __restrict__ b, float* __restrict__ out,
                            int N, int Cin, int H, int W, int Cout, int OH, int OW,
                            int K, int stride, int pad, int relu)
{
    int idx = blockIdx.x * blockDim.x + threadIdx.x;
    int total = N * Cout * OH * OW;
    if (idx >= total) return;
    int ow = idx % OW;
    int oh = (idx / OW) % OH;
    int co = (idx / (OW * OH)) % Cout;
    int n  = idx / (OW * OH * Cout);

    float acc = b[co];
    int ih0 = oh * stride - pad;
    int iw0 = ow * stride - pad;
    const float* wbase = w + (size_t)co * Cin * K * K;
    const float* ibase = in + (size_t)n * Cin * H * W;
    for (int ci = 0; ci < Cin; ++ci) {
        const float* ip = ibase + (size_t)ci * H * W;
        const float* wp = wbase + ci * K * K;
        for (int kh = 0; kh < K; ++kh) {
            int ih = ih0 + kh;
            if (ih < 0 || ih >= H) continue;
            const float* irow = ip + ih * W;
            const float* wrow = wp + kh * K;
            for (int kw = 0; kw < K; ++kw) {
                int iw = iw0 + kw;
                if (iw < 0 || iw >= W) continue;
                acc = fmaf(irow[iw], wrow[kw], acc);
            }
        }
    }
    if (relu) acc = fmaxf(acc, 0.f);
    out[idx] = acc;
}

// ---------------------------------------------------------------------------
// Instance norm, in place, one 256-thread block per (n,c) plane. Optional ReLU after.
// ---------------------------------------------------------------------------
__global__ void inorm_block(float* __restrict__ data, int HW, int relu)
{
    float* p = data + (size_t)blockIdx.x * HW;
    __shared__ float ssum[256], ssq[256];
    float s = 0.f, q = 0.f;
    for (int i = threadIdx.x; i < HW; i += blockDim.x) {
        float v = p[i]; s += v; q += v * v;
    }
    ssum[threadIdx.x] = s; ssq[threadIdx.x] = q;
    __syncthreads();
    for (int off = blockDim.x / 2; off > 0; off >>= 1) {
        if ((int)threadIdx.x < off) {
            ssum[threadIdx.x] += ssum[threadIdx.x + off];
            ssq[threadIdx.x]  += ssq[threadIdx.x + off];
        }
        __syncthreads();
    }
    float m = ssum[0] / (float)HW;
    float v = ssq[0] / (float)HW - m * m;
    float r = rsqrtf(v + EPS);
    for (int i = threadIdx.x; i < HW; i += blockDim.x) {
        float y = (p[i] - m) * r;
        if (relu) y = fmaxf(y, 0.f);
        p[i] = y;
    }
}

// ---------------------------------------------------------------------------
// Instance norm, in place, one 64-lane wave per (n,c) plane (small HW layers).
// ---------------------------------------------------------------------------
__global__ void inorm_wave(float* __restrict__ data, int nplanes, int HW, int relu)
{
    int gid  = blockIdx.x * blockDim.x + threadIdx.x;
    int wave = gid >> 6;
    int lane = gid & 63;
    if (wave >= nplanes) return;
    float* p = data + (size_t)wave * HW;
    float s = 0.f, q = 0.f;
    for (int i = lane; i < HW; i += 64) {
        float v = p[i]; s += v; q += v * v;
    }
    for (int m = 32; m >= 1; m >>= 1) {
        s += __shfl_xor(s, m);
        q += __shfl_xor(q, m);
    }
    float mean = s / (float)HW;
    float var  = q / (float)HW - mean * mean;
    float r = rsqrtf(var + EPS);
    for (int i = lane; i < HW; i += 64) {
        float y = (p[i] - mean) * r;
        if (relu) y = fmaxf(y, 0.f);
        p[i] = y;
    }
}

// ---------------------------------------------------------------------------
// Maxpool (64,256,4,3) -> (64,512): f = c*2 + h, max over rows {2h,2h+1} x cols {0,1}
// ---------------------------------------------------------------------------
__global__ void pool_kernel(const float* __restrict__ in, float* __restrict__ out)
{
    int idx = blockIdx.x * blockDim.x + threadIdx.x;
    if (idx >= 64 * 512) return;
    int f = idx & 511;
    int n = idx >> 9;
    int c = f >> 1;
    int h = f & 1;
    const float* p = in + (((size_t)n * 256 + c) * 4 + h * 2) * 3;
    out[idx] = fmaxf(fmaxf(p[0], p[1]), fmaxf(p[3], p[4]));
}

// fc1: (64,512) @ (128,512)^T + b, relu -> (64,128)
__global__ void fc1_kernel(const float* __restrict__ in, const float* __restrict__ w,
                           const float* __restrict__ b, float* __restrict__ out)
{
    int idx = blockIdx.x * blockDim.x + threadIdx.x;
    if (idx >= 64 * 128) return;
    int j = idx & 127;
    int n = idx >> 7;
    const float* x  = in + n * 512;
    const float* wr = w + j * 512;
    float acc = b[j];
    for (int f = 0; f < 512; ++f) acc = fmaf(x[f], wr[f], acc);
    out[idx] = fmaxf(acc, 0.f);
}

// fc2: (64,128) @ (50,128)^T + b, tanh -> writes coor directly into d_out[0:3200]
__global__ void fc2_kernel(const float* __restrict__ in, const float* __restrict__ w,
                           const float* __restrict__ b, float* __restrict__ out)
{
    int idx = blockIdx.x * blockDim.x + threadIdx.x;
    if (idx >= 64 * 50) return;
    int k = idx % 50;
    int n = idx / 50;
    const float* x  = in + n * 128;
    const float* wr = w + k * 128;
    float acc = b[k];
    for (int f = 0; f < 128; ++f) acc = fmaf(x[f], wr[f], acc);
    out[idx] = tanhf(acc);
}

// ---------------------------------------------------------------------------
// Losses. pts = d_out[0:3200] as (64,50); grid[n][r][c][d] = pts[n*50+(r*5+c)*2+d]
// ---------------------------------------------------------------------------
__global__ void loss_kernel(const float* __restrict__ pts, float* __restrict__ out)
{
    __shared__ float acc[4][64];
    int n = threadIdx.x;
    float rx = 0.f, ry = 0.f, cx = 0.f, cy = 0.f;
    {
        const float* g = pts + n * 50;
        // rows: vary col index j along axis=2
        for (int r = 0; r < 5; ++r)
            for (int j = 0; j < 3; ++j)
                for (int d = 0; d < 2; ++d) {
                    float a0 = g[(r * 5 + j) * 2 + d];
                    float a1 = g[(r * 5 + j + 1) * 2 + d];
                    float a2 = g[(r * 5 + j + 2) * 2 + d];
                    float d0 = (a1 - a0) * (a1 - a0);
                    float d1 = (a2 - a1) * (a2 - a1);
                    float t = fmaxf(0.08f, fabsf(d1 - d0));
                    if (d == 0) rx += t; else ry += t;
                }
        // cols: transposed
        for (int r = 0; r < 5; ++r)
            for (int j = 0; j < 3; ++j)
                for (int d = 0; d < 2; ++d) {
                    float a0 = g[(j * 5 + r) * 2 + d];
                    float a1 = g[((j + 1) * 5 + r) * 2 + d];
                    float a2 = g[((j + 2) * 5 + r) * 2 + d];
                    float d0 = (a1 - a0) * (a1 - a0);
                    float d1 = (a2 - a1) * (a2 - a1);
                    float t = fmaxf(0.08f, fabsf(d1 - d0));
                    if (d == 0) cx += t; else cy += t;
                }
    }
    acc[0][n] = rx; acc[1][n] = ry; acc[2][n] = cx; acc[3][n] = cy;
    __syncthreads();
    if (n == 0) {
        float s0 = 0.f, s1 = 0.f, s2 = 0.f, s3 = 0.f;
        for (int i = 0; i < 64; ++i) {
            s0 += acc[0][i]; s1 += acc[1][i]; s2 += acc[2][i]; s3 += acc[3][i];
        }
        float inv = 1.0f / (64.0f * 15.0f);
        out[3200] = s0 * inv;
        out[3201] = s1 * inv;
        out[3202] = s2 * inv;
        out[3203] = s3 * inv;
        // curvature losses on batch 0
        const float* g = pts;
        float rg = 0.f, cg = 0.f;
        for (int r = 0; r < 5; ++r)
            for (int j = 0; j < 3; ++j) {
                float x0 = g[(r * 5 + j) * 2],     y0 = g[(r * 5 + j) * 2 + 1];
                float x1 = g[(r * 5 + j + 1) * 2], y1 = g[(r * 5 + j + 1) * 2 + 1];
                float x2 = g[(r * 5 + j + 2) * 2], y2 = g[(r * 5 + j + 2) * 2 + 1];
                rg += fabsf((y1 - y0) * (x1 - x2) - (y1 - y2) * (x1 - x0));
            }
        for (int r = 0; r < 5; ++r)
            for (int j = 0; j < 3; ++j) {
                float x0 = g[(j * 5 + r) * 2],       y0 = g[(j * 5 + r) * 2 + 1];
                float x1 = g[((j + 1) * 5 + r) * 2], y1 = g[((j + 1) * 5 + r) * 2 + 1];
                float x2 = g[((j + 2) * 5 + r) * 2], y2 = g[((j + 2) * 5 + r) * 2 + 1];
                cg += fabsf((y1 - y0) * (x1 - x2) - (y1 - y2) * (x1 - x0));
            }
        out[3204] = fmaxf(rg, 0.02f);
        out[3205] = fmaxf(cg, 0.02f);
    }
}

extern "C" void kernel_launch(void* const* d_in, const int* in_sizes, int n_in,
                              void* d_out, int out_size, void* d_ws, size_t ws_size,
                              hipStream_t stream)
{
    const float* x     = (const float*)d_in[0];
    const float* w[8], *bia[8];
    for (int i = 0; i < 6; ++i) { w[i] = (const float*)d_in[1 + 2 * i]; bia[i] = (const float*)d_in[2 + 2 * i]; }
    w[6] = (const float*)d_in[13]; bia[6] = (const float*)d_in[14];
    w[7] = (const float*)d_in[15]; bia[7] = (const float*)d_in[16];
    const float* fc1_w = (const float*)d_in[17];
    const float* fc1_b = (const float*)d_in[18];
    const float* fc2_w = (const float*)d_in[19];
    const float* fc2_b = (const float*)d_in[20];
    float* out = (float*)d_out;

    // workspace layout (floats)
    float* A      = (float*)d_ws;                 // 6,291,456
    float* Bf     = A + 6291456;                  // 3,145,728
    float* pooled = Bf + 3145728;                 // 32,768
    float* fc1o   = pooled + 32768;               // 8,192

    const int N = 64;
    // layer configs: Cin,H,W,Cout,OH,OW,K,stride
    struct LC { int ci, h, wd, co, oh, ow, k, s; };
    const LC lc[8] = {
        {5,   256, 192, 8,   128, 96, 4, 2},
        {8,   128, 96,  16,  64,  48, 4, 2},
        {16,  64,  48,  32,  32,  24, 4, 2},
        {32,  32,  24,  64,  16,  12, 4, 2},
        {64,  16,  12,  128, 8,   6,  4, 2},
        {128, 8,   6,   256, 4,   3,  4, 2},
        {256, 4,   3,   256, 4,   3,  3, 1},
        {256, 4,   3,   256, 4,   3,  3, 1},
    };

    const float* cur = x;
    float* bufs[2] = {A, Bf};
    for (int i = 0; i < 8; ++i) {
        float* dst = bufs[i & 1];            // L0->A, L1->B, L2->A, ...
        int total = N * lc[i].co * lc[i].oh * lc[i].ow;
        int blocks = (total + 255) / 256;
        int conv_relu = (i == 0) ? 1 : 0;    // layer0: relu BEFORE norm
        conv_kernel<<<blocks, 256, 0, stream>>>(cur, w[i], bia[i], dst,
            N, lc[i].ci, lc[i].h, lc[i].wd, lc[i].co, lc[i].oh, lc[i].ow,
            lc[i].k, lc[i].s, 1, conv_relu);

        int planes = N * lc[i].co;
        int HW = lc[i].oh * lc[i].ow;
        int norm_relu = (i == 0) ? 0 : 1;    // layers 1..7: relu AFTER norm
        if (HW >= 768) {
            inorm_block<<<planes, 256, 0, stream>>>(dst, HW, norm_relu);
        } else {
            int nthr = planes * 64;
            inorm_wave<<<(nthr + 255) / 256, 256, 0, stream>>>(dst, planes, HW, norm_relu);
        }
        cur = dst;
    }

    pool_kernel<<<(64 * 512 + 255) / 256, 256, 0, stream>>>(cur, pooled);
    fc1_kernel<<<(64 * 128 + 255) / 256, 256, 0, stream>>>(pooled, fc1_w, fc1_b, fc1o);
    fc2_kernel<<<(64 * 50 + 255) / 256, 256, 0, stream>>>(fc1o, fc2_w, fc2_b, out);
    loss_kernel<<<1, 64, 0, stream>>>(out, out);
}

// Round 2
// 1405.895 us; speedup vs baseline: 1.9308x; 1.9308x over previous
//
#include <hip/hip_runtime.h>
#include <hip/hip_bf16.h>
#include <math.h>

#define EPS 1e-5f

// ---------------------------------------------------------------------------
// Kernel A: K=4, stride=2, pad=1 conv. One thread per output pixel, CPT output
// channels per thread (CPT accumulators). Block weights staged in LDS.
// Requires: blockDim == min(256, OH*OW); each block covers exactly one (n, cg).
// ---------------------------------------------------------------------------
template<int CIN, int CPT>
__global__ void conv42(const float* __restrict__ in, const float* __restrict__ w,
                       const float* __restrict__ bias, float* __restrict__ out,
                       int N, int H, int W, int COUT, int OH, int OW, int relu)
{
    const int NPX = OH * OW;
    const int PXB = NPX / blockDim.x;          // px-blocks per (n,cg)
    const int NCG = COUT / CPT;

    int bx  = blockIdx.x;
    int pxb = bx % PXB;
    int cg  = (bx / PXB) % NCG;
    int n   = bx / (PXB * NCG);
    int tid = threadIdx.x;

    __shared__ float sW[CPT * CIN * 16];
    // stage weights transposed to [ci][j][16] for contiguous b128 reads
    for (int i = tid; i < CPT * CIN * 16; i += blockDim.x) {
        int ci = i / (CPT * 16);
        int r  = i % (CPT * 16);
        int j  = r / 16;
        int k  = r % 16;
        sW[i] = w[((size_t)(cg * CPT + j) * CIN + ci) * 16 + k];
    }
    __syncthreads();

    int px = pxb * blockDim.x + tid;
    int oh = px / OW, ow = px % OW;
    int ih0 = oh * 2 - 1, iw0 = ow * 2 - 1;

    float acc[CPT];
#pragma unroll
    for (int j = 0; j < CPT; ++j) acc[j] = bias[cg * CPT + j];

    const float* ib = in + (size_t)n * CIN * H * W;
    for (int ci = 0; ci < CIN; ++ci) {
        float p[16];
        const float* plane = ib + (size_t)ci * H * W;
#pragma unroll
        for (int kh = 0; kh < 4; ++kh) {
            int ih = ih0 + kh;
            bool vr = (unsigned)ih < (unsigned)H;
            const float* row = plane + (size_t)ih * W;
#pragma unroll
            for (int kw = 0; kw < 4; ++kw) {
                int iw = iw0 + kw;
                bool v = vr && ((unsigned)iw < (unsigned)W);
                p[kh * 4 + kw] = v ? row[iw] : 0.f;
            }
        }
        const float* wp = sW + ci * CPT * 16;
#pragma unroll
        for (int j = 0; j < CPT; ++j) {
            const float* wj = wp + j * 16;
#pragma unroll
            for (int k = 0; k < 16; ++k) acc[j] = fmaf(p[k], wj[k], acc[j]);
        }
    }

#pragma unroll
    for (int j = 0; j < CPT; ++j) {
        float v = acc[j];
        if (relu) v = fmaxf(v, 0.f);
        out[((size_t)(n * COUT + cg * CPT + j) * OH + oh) * OW + ow] = v;
    }
}

// ---------------------------------------------------------------------------
// Kernel B: whole (padded) input image for one n staged in LDS; weights staged
// in ci-chunks of CIC. Thread = (px, co-group of CPT). pad=1 assumed.
// K=3 weights are zero-padded to rows of 4 so patch rows read as quads.
// ---------------------------------------------------------------------------
template<int CIN, int H, int W, int COUT, int K, int S, int TCO, int CPT, int CIC>
__global__ void conv_lds(const float* __restrict__ in, const float* __restrict__ w,
                         const float* __restrict__ bias, float* __restrict__ out, int relu)
{
    constexpr int HP = H + 2, WP = W + 2;
    constexpr int OH = (H + 2 - K) / S + 1;
    constexpr int OW = (W + 2 - K) / S + 1;
    constexpr int PX = OH * OW;
    constexpr int NCG = TCO / CPT;
    constexpr int NT  = PX * NCG;
    constexpr int KKP = (K == 3) ? 12 : 16;

    __shared__ float sIn[CIN * HP * WP + 4];
    __shared__ float sW[TCO * CIC * KKP];

    int t  = threadIdx.x;
    int ct = blockIdx.x % (COUT / TCO);
    int n  = blockIdx.x / (COUT / TCO);

    // stage padded input image (coalesced; zero borders)
    for (int i = t; i < CIN * HP * WP; i += NT) {
        int ci  = i / (HP * WP);
        int r   = i % (HP * WP);
        int ihp = r / WP, iwp = r % WP;
        int ih = ihp - 1, iw = iwp - 1;
        float v = 0.f;
        if ((unsigned)ih < (unsigned)H && (unsigned)iw < (unsigned)W)
            v = in[((size_t)(n * CIN + ci) * H + ih) * W + iw];
        sIn[i] = v;
    }
    if (t < 4) sIn[CIN * HP * WP + t] = 0.f;   // guard pad for K=3 quad reads

    int px = t % PX;
    int cg = t / PX;
    int oh = px / OW, ow = px % OW;
    int cob = ct * TCO + cg * CPT;

    float acc[CPT];
#pragma unroll
    for (int j = 0; j < CPT; ++j) acc[j] = bias[cob + j];

    for (int cc = 0; cc < CIN; cc += CIC) {
        __syncthreads();   // first iter: finish sIn; later: protect sW overwrite
        // stage weight chunk: layout sW[(ci*TCO + co)*KKP + k]
        for (int i = t; i < TCO * CIC * KKP; i += NT) {
            int ci = i / (TCO * KKP);
            int r  = i % (TCO * KKP);
            int co = r / KKP;
            int k  = r % KKP;
            float v = 0.f;
            if (K == 4) {
                v = w[((size_t)(ct * TCO + co) * CIN + cc + ci) * 16 + k];
            } else {
                int kr = k >> 2, kc = k & 3;
                if (kc < 3 && kr < 3)
                    v = w[((size_t)(ct * TCO + co) * CIN + cc + ci) * 9 + kr * 3 + kc];
            }
            sW[i] = v;
        }
        __syncthreads();

#pragma unroll 1
        for (int cil = 0; cil < CIC; ++cil) {
            const float* pin = sIn + (cc + cil) * HP * WP + (oh * S) * WP + (ow * S);
            float p[K * 4];
#pragma unroll
            for (int kh = 0; kh < K; ++kh)
#pragma unroll
                for (int c = 0; c < 4; ++c) p[kh * 4 + c] = pin[kh * WP + c];
            const float* wp_ = sW + (cil * TCO + cg * CPT) * KKP;
#pragma unroll
            for (int j = 0; j < CPT; ++j) {
                const float* wj = wp_ + j * KKP;
#pragma unroll
                for (int k = 0; k < K * 4; ++k) acc[j] = fmaf(p[k], wj[k], acc[j]);
            }
        }
    }

#pragma unroll
    for (int j = 0; j < CPT; ++j) {
        float v = acc[j];
        if (relu) v = fmaxf(v, 0.f);
        out[((size_t)(n * COUT + cob + j) * OH + oh) * OW + ow] = v;
    }
}

// ---------------------------------------------------------------------------
// Instance norm (block variant, large planes)
// ---------------------------------------------------------------------------
__global__ void inorm_block(float* __restrict__ data, int HW, int relu)
{
    float* p = data + (size_t)blockIdx.x * HW;
    __shared__ float ssum[256], ssq[256];
    float s = 0.f, q = 0.f;
    for (int i = threadIdx.x; i < HW; i += blockDim.x) {
        float v = p[i]; s += v; q += v * v;
    }
    ssum[threadIdx.x] = s; ssq[threadIdx.x] = q;
    __syncthreads();
    for (int off = blockDim.x / 2; off > 0; off >>= 1) {
        if ((int)threadIdx.x < off) {
            ssum[threadIdx.x] += ssum[threadIdx.x + off];
            ssq[threadIdx.x]  += ssq[threadIdx.x + off];
        }
        __syncthreads();
    }
    float m = ssum[0] / (float)HW;
    float v = ssq[0] / (float)HW - m * m;
    float r = rsqrtf(v + EPS);
    for (int i = threadIdx.x; i < HW; i += blockDim.x) {
        float y = (p[i] - m) * r;
        if (relu) y = fmaxf(y, 0.f);
        p[i] = y;
    }
}

// Instance norm (wave variant, small planes)
__global__ void inorm_wave(float* __restrict__ data, int nplanes, int HW, int relu)
{
    int gid  = blockIdx.x * blockDim.x + threadIdx.x;
    int wave = gid >> 6;
    int lane = gid & 63;
    if (wave >= nplanes) return;
    float* p = data + (size_t)wave * HW;
    float s = 0.f, q = 0.f;
    for (int i = lane; i < HW; i += 64) {
        float v = p[i]; s += v; q += v * v;
    }
    for (int m = 32; m >= 1; m >>= 1) {
        s += __shfl_xor(s, m);
        q += __shfl_xor(q, m);
    }
    float mean = s / (float)HW;
    float var  = q / (float)HW - mean * mean;
    float r = rsqrtf(var + EPS);
    for (int i = lane; i < HW; i += 64) {
        float y = (p[i] - mean) * r;
        if (relu) y = fmaxf(y, 0.f);
        p[i] = y;
    }
}

// maxpool (64,256,4,3) -> (64,512)
__global__ void pool_kernel(const float* __restrict__ in, float* __restrict__ out)
{
    int idx = blockIdx.x * blockDim.x + threadIdx.x;
    if (idx >= 64 * 512) return;
    int f = idx & 511;
    int n = idx >> 9;
    int c = f >> 1;
    int h = f & 1;
    const float* p = in + (((size_t)n * 256 + c) * 4 + h * 2) * 3;
    out[idx] = fmaxf(fmaxf(p[0], p[1]), fmaxf(p[3], p[4]));
}

__global__ void fc1_kernel(const float* __restrict__ in, const float* __restrict__ w,
                           const float* __restrict__ b, float* __restrict__ out)
{
    int idx = blockIdx.x * blockDim.x + threadIdx.x;
    if (idx >= 64 * 128) return;
    int j = idx & 127;
    int n = idx >> 7;
    const float* x  = in + n * 512;
    const float* wr = w + j * 512;
    float acc = b[j];
    for (int f = 0; f < 512; ++f) acc = fmaf(x[f], wr[f], acc);
    out[idx] = fmaxf(acc, 0.f);
}

__global__ void fc2_kernel(const float* __restrict__ in, const float* __restrict__ w,
                           const float* __restrict__ b, float* __restrict__ out)
{
    int idx = blockIdx.x * blockDim.x + threadIdx.x;
    if (idx >= 64 * 50) return;
    int k = idx % 50;
    int n = idx / 50;
    const float* x  = in + n * 128;
    const float* wr = w + k * 128;
    float acc = b[k];
    for (int f = 0; f < 128; ++f) acc = fmaf(x[f], wr[f], acc);
    out[idx] = tanhf(acc);
}

__global__ void loss_kernel(const float* __restrict__ pts, float* __restrict__ out)
{
    __shared__ float acc[4][64];
    int n = threadIdx.x;
    float rx = 0.f, ry = 0.f, cx = 0.f, cy = 0.f;
    {
        const float* g = pts + n * 50;
        for (int r = 0; r < 5; ++r)
            for (int j = 0; j < 3; ++j)
                for (int d = 0; d < 2; ++d) {
                    float a0 = g[(r * 5 + j) * 2 + d];
                    float a1 = g[(r * 5 + j + 1) * 2 + d];
                    float a2 = g[(r * 5 + j + 2) * 2 + d];
                    float d0 = (a1 - a0) * (a1 - a0);
                    float d1 = (a2 - a1) * (a2 - a1);
                    float t = fmaxf(0.08f, fabsf(d1 - d0));
                    if (d == 0) rx += t; else ry += t;
                }
        for (int r = 0; r < 5; ++r)
            for (int j = 0; j < 3; ++j)
                for (int d = 0; d < 2; ++d) {
                    float a0 = g[(j * 5 + r) * 2 + d];
                    float a1 = g[((j + 1) * 5 + r) * 2 + d];
                    float a2 = g[((j + 2) * 5 + r) * 2 + d];
                    float d0 = (a1 - a0) * (a1 - a0);
                    float d1 = (a2 - a1) * (a2 - a1);
                    float t = fmaxf(0.08f, fabsf(d1 - d0));
                    if (d == 0) cx += t; else cy += t;
                }
    }
    acc[0][n] = rx; acc[1][n] = ry; acc[2][n] = cx; acc[3][n] = cy;
    __syncthreads();
    if (n == 0) {
        float s0 = 0.f, s1 = 0.f, s2 = 0.f, s3 = 0.f;
        for (int i = 0; i < 64; ++i) {
            s0 += acc[0][i]; s1 += acc[1][i]; s2 += acc[2][i]; s3 += acc[3][i];
        }
        float inv = 1.0f / (64.0f * 15.0f);
        out[3200] = s0 * inv;
        out[3201] = s1 * inv;
        out[3202] = s2 * inv;
        out[3203] = s3 * inv;
        const float* g = pts;
        float rg = 0.f, cg = 0.f;
        for (int r = 0; r < 5; ++r)
            for (int j = 0; j < 3; ++j) {
                float x0 = g[(r * 5 + j) * 2],     y0 = g[(r * 5 + j) * 2 + 1];
                float x1 = g[(r * 5 + j + 1) * 2], y1 = g[(r * 5 + j + 1) * 2 + 1];
                float x2 = g[(r * 5 + j + 2) * 2], y2 = g[(r * 5 + j + 2) * 2 + 1];
                rg += fabsf((y1 - y0) * (x1 - x2) - (y1 - y2) * (x1 - x0));
            }
        for (int r = 0; r < 5; ++r)
            for (int j = 0; j < 3; ++j) {
                float x0 = g[(j * 5 + r) * 2],       y0 = g[(j * 5 + r) * 2 + 1];
                float x1 = g[((j + 1) * 5 + r) * 2], y1 = g[((j + 1) * 5 + r) * 2 + 1];
                float x2 = g[((j + 2) * 5 + r) * 2], y2 = g[((j + 2) * 5 + r) * 2 + 1];
                cg += fabsf((y1 - y0) * (x1 - x2) - (y1 - y2) * (x1 - x0));
            }
        out[3204] = fmaxf(rg, 0.02f);
        out[3205] = fmaxf(cg, 0.02f);
    }
}

extern "C" void kernel_launch(void* const* d_in, const int* in_sizes, int n_in,
                              void* d_out, int out_size, void* d_ws, size_t ws_size,
                              hipStream_t stream)
{
    const float* x = (const float*)d_in[0];
    const float* w[8], *bia[8];
    for (int i = 0; i < 6; ++i) { w[i] = (const float*)d_in[1 + 2 * i]; bia[i] = (const float*)d_in[2 + 2 * i]; }
    w[6] = (const float*)d_in[13]; bia[6] = (const float*)d_in[14];
    w[7] = (const float*)d_in[15]; bia[7] = (const float*)d_in[16];
    const float* fc1_w = (const float*)d_in[17];
    const float* fc1_b = (const float*)d_in[18];
    const float* fc2_w = (const float*)d_in[19];
    const float* fc2_b = (const float*)d_in[20];
    float* out = (float*)d_out;

    float* A      = (float*)d_ws;                 // ping
    float* Bf     = A + 6291456;                  // pong
    float* pooled = Bf + 3145728;
    float* fc1o   = pooled + 32768;

    const int N = 64;
    const float* cur = x;
    float* bufs[2] = {A, Bf};

    // ---- L0: (5,256,192) -> (8,128,96), conv+relu then norm ----
    {
        float* dst = bufs[0];
        // grid = N * NCG * PXB = 64*1*(12288/256)=3072
        conv42<5, 8><<<3072, 256, 0, stream>>>(cur, w[0], bia[0], dst, N, 256, 192, 8, 128, 96, 1);
        inorm_block<<<N * 8, 256, 0, stream>>>(dst, 128 * 96, 0);
        cur = dst;
    }
    // ---- L1: (8,128,96) -> (16,64,48) ----
    {
        float* dst = bufs[1];
        conv42<8, 16><<<768, 256, 0, stream>>>(cur, w[1], bia[1], dst, N, 128, 96, 16, 64, 48, 0);
        inorm_block<<<N * 16, 256, 0, stream>>>(dst, 64 * 48, 1);
        cur = dst;
    }
    // ---- L2: (16,64,48) -> (32,32,24) ----
    {
        float* dst = bufs[0];
        conv42<16, 16><<<384, 256, 0, stream>>>(cur, w[2], bia[2], dst, N, 64, 48, 32, 32, 24, 0);
        inorm_block<<<N * 32, 256, 0, stream>>>(dst, 32 * 24, 1);
        cur = dst;
    }
    // ---- L3: (32,32,24) -> (64,16,12), NPX=192 -> blockDim 192 ----
    {
        float* dst = bufs[1];
        conv42<32, 8><<<512, 192, 0, stream>>>(cur, w[3], bia[3], dst, N, 32, 24, 64, 16, 12, 0);
        int planes = N * 64, HW = 192;
        inorm_wave<<<(planes * 64 + 255) / 256, 256, 0, stream>>>(dst, planes, HW, 1);
        cur = dst;
    }
    // ---- L4: (64,16,12) -> (128,8,6) ----
    {
        float* dst = bufs[0];
        conv_lds<64, 16, 12, 128, 4, 2, 16, 4, 8><<<512, 192, 0, stream>>>(cur, w[4], bia[4], dst, 0);
        int planes = N * 128, HW = 48;
        inorm_wave<<<(planes * 64 + 255) / 256, 256, 0, stream>>>(dst, planes, HW, 1);
        cur = dst;
    }
    // ---- L5: (128,8,6) -> (256,4,3) ----
    {
        float* dst = bufs[1];
        conv_lds<128, 8, 6, 256, 4, 2, 64, 4, 8><<<256, 192, 0, stream>>>(cur, w[5], bia[5], dst, 0);
        int planes = N * 256, HW = 12;
        inorm_wave<<<(planes * 64 + 255) / 256, 256, 0, stream>>>(dst, planes, HW, 1);
        cur = dst;
    }
    // ---- L6, L7: (256,4,3) -> (256,4,3), K=3 s=1 ----
    for (int i = 6; i < 8; ++i) {
        float* dst = bufs[i & 1];
        conv_lds<256, 4, 3, 256, 3, 1, 64, 4, 8><<<256, 192, 0, stream>>>(cur, w[i], bia[i], dst, 0);
        int planes = N * 256, HW = 12;
        inorm_wave<<<(planes * 64 + 255) / 256, 256, 0, stream>>>(dst, planes, HW, 1);
        cur = dst;
    }

    pool_kernel<<<(64 * 512 + 255) / 256, 256, 0, stream>>>(cur, pooled);
    fc1_kernel<<<(64 * 128 + 255) / 256, 256, 0, stream>>>(pooled, fc1_w, fc1_b, fc1o);
    fc2_kernel<<<(64 * 50 + 255) / 256, 256, 0, stream>>>(fc1o, fc2_w, fc2_b, out);
    loss_kernel<<<1, 64, 0, stream>>>(out, out);
}

// Round 3
// 606.130 us; speedup vs baseline: 4.4784x; 2.3195x over previous
//
#include <hip/hip_runtime.h>
#include <hip/hip_bf16.h>
#include <math.h>

#define EPS 1e-5f

// ---------------------------------------------------------------------------
// Kernel A: K=4, stride=2, pad=1 conv. One thread per output pixel, CPT output
// channels per thread. Block weights staged in LDS. (Layers 0-3.)
// ---------------------------------------------------------------------------
template<int CIN, int CPT>
__global__ void conv42(const float* __restrict__ in, const float* __restrict__ w,
                       const float* __restrict__ bias, float* __restrict__ out,
                       int N, int H, int W, int COUT, int OH, int OW, int relu)
{
    const int NPX = OH * OW;
    const int PXB = NPX / blockDim.x;
    const int NCG = COUT / CPT;

    int bx  = blockIdx.x;
    int pxb = bx % PXB;
    int cg  = (bx / PXB) % NCG;
    int n   = bx / (PXB * NCG);
    int tid = threadIdx.x;

    __shared__ float sW[CPT * CIN * 16];
    for (int i = tid; i < CPT * CIN * 16; i += blockDim.x) {
        int ci = i / (CPT * 16);
        int r  = i % (CPT * 16);
        int j  = r / 16;
        int k  = r % 16;
        sW[i] = w[((size_t)(cg * CPT + j) * CIN + ci) * 16 + k];
    }
    __syncthreads();

    int px = pxb * blockDim.x + tid;
    int oh = px / OW, ow = px % OW;
    int ih0 = oh * 2 - 1, iw0 = ow * 2 - 1;

    float acc[CPT];
#pragma unroll
    for (int j = 0; j < CPT; ++j) acc[j] = bias[cg * CPT + j];

    const float* ib = in + (size_t)n * CIN * H * W;
    for (int ci = 0; ci < CIN; ++ci) {
        float p[16];
        const float* plane = ib + (size_t)ci * H * W;
#pragma unroll
        for (int kh = 0; kh < 4; ++kh) {
            int ih = ih0 + kh;
            bool vr = (unsigned)ih < (unsigned)H;
            const float* row = plane + (size_t)ih * W;
#pragma unroll
            for (int kw = 0; kw < 4; ++kw) {
                int iw = iw0 + kw;
                bool v = vr && ((unsigned)iw < (unsigned)W);
                p[kh * 4 + kw] = v ? row[iw] : 0.f;
            }
        }
        const float* wp = sW + ci * CPT * 16;
#pragma unroll
        for (int j = 0; j < CPT; ++j) {
            const float* wj = wp + j * 16;
#pragma unroll
            for (int k = 0; k < 16; ++k) acc[j] = fmaf(p[k], wj[k], acc[j]);
        }
    }

#pragma unroll
    for (int j = 0; j < CPT; ++j) {
        float v = acc[j];
        if (relu) v = fmaxf(v, 0.f);
        out[((size_t)(n * COUT + cg * CPT + j) * OH + oh) * OW + ow] = v;
    }
}

// ---------------------------------------------------------------------------
// Kernel B (layer 4 only now): whole padded image in LDS.
// ---------------------------------------------------------------------------
template<int CIN, int H, int W, int COUT, int K, int S, int TCO, int CPT, int CIC>
__global__ void conv_lds(const float* __restrict__ in, const float* __restrict__ w,
                         const float* __restrict__ bias, float* __restrict__ out, int relu)
{
    constexpr int HP = H + 2, WP = W + 2;
    constexpr int OH = (H + 2 - K) / S + 1;
    constexpr int OW = (W + 2 - K) / S + 1;
    constexpr int PX = OH * OW;
    constexpr int NCG = TCO / CPT;
    constexpr int NT  = PX * NCG;
    constexpr int KKP = (K == 3) ? 12 : 16;

    __shared__ float sIn[CIN * HP * WP + 4];
    __shared__ float sW[TCO * CIC * KKP];

    int t  = threadIdx.x;
    int ct = blockIdx.x % (COUT / TCO);
    int n  = blockIdx.x / (COUT / TCO);

    for (int i = t; i < CIN * HP * WP; i += NT) {
        int ci  = i / (HP * WP);
        int r   = i % (HP * WP);
        int ihp = r / WP, iwp = r % WP;
        int ih = ihp - 1, iw = iwp - 1;
        float v = 0.f;
        if ((unsigned)ih < (unsigned)H && (unsigned)iw < (unsigned)W)
            v = in[((size_t)(n * CIN + ci) * H + ih) * W + iw];
        sIn[i] = v;
    }
    if (t < 4) sIn[CIN * HP * WP + t] = 0.f;

    int px = t % PX;
    int cg = t / PX;
    int oh = px / OW, ow = px % OW;
    int cob = ct * TCO + cg * CPT;

    float acc[CPT];
#pragma unroll
    for (int j = 0; j < CPT; ++j) acc[j] = bias[cob + j];

    for (int cc = 0; cc < CIN; cc += CIC) {
        __syncthreads();
        for (int i = t; i < TCO * CIC * KKP; i += NT) {
            int ci = i / (TCO * KKP);
            int r  = i % (TCO * KKP);
            int co = r / KKP;
            int k  = r % KKP;
            float v = 0.f;
            if (K == 4) {
                v = w[((size_t)(ct * TCO + co) * CIN + cc + ci) * 16 + k];
            } else {
                int kr = k >> 2, kc = k & 3;
                if (kc < 3 && kr < 3)
                    v = w[((size_t)(ct * TCO + co) * CIN + cc + ci) * 9 + kr * 3 + kc];
            }
            sW[i] = v;
        }
        __syncthreads();

#pragma unroll 1
        for (int cil = 0; cil < CIC; ++cil) {
            const float* pin = sIn + (cc + cil) * HP * WP + (oh * S) * WP + (ow * S);
            float p[K * 4];
#pragma unroll
            for (int kh = 0; kh < K; ++kh)
#pragma unroll
                for (int c = 0; c < 4; ++c) p[kh * 4 + c] = pin[kh * WP + c];
            const float* wp_ = sW + (cil * TCO + cg * CPT) * KKP;
#pragma unroll
            for (int j = 0; j < CPT; ++j) {
                const float* wj = wp_ + j * KKP;
#pragma unroll
                for (int k = 0; k < K * 4; ++k) acc[j] = fmaf(p[k], wj[k], acc[j]);
            }
        }
    }

#pragma unroll
    for (int j = 0; j < CPT; ++j) {
        float v = acc[j];
        if (relu) v = fmaxf(v, 0.f);
        out[((size_t)(n * COUT + cob + j) * OH + oh) * OW + ow] = v;
    }
}

// ---------------------------------------------------------------------------
// Layer 6/7 conv: (256,4,3)->(256,4,3), K=3,S=1,pad=1. lane=n, wave=(cog,cic).
// Weights are wave-uniform (scalarized); no LDS; all 12 px in registers.
// Writes partials (no bias: it cancels under the following instance norm).
// ---------------------------------------------------------------------------
__global__ __launch_bounds__(256) void conv_l67(const float* __restrict__ in,
                                                const float* __restrict__ w,
                                                float* __restrict__ pbuf)
{
    int t    = threadIdx.x;
    int gw   = blockIdx.x * 4 + (t >> 6);   // 0..1023
    int lane = t & 63;                      // = n
    int cic  = gw >> 6;                     // 0..15
    int cog  = gw & 63;                     // 0..63
    int cc   = cic * 16;
    int co0  = cog * 4;

    float acc[4][12];
#pragma unroll
    for (int j = 0; j < 4; ++j)
#pragma unroll
        for (int p = 0; p < 12; ++p) acc[j][p] = 0.f;

    const float* ip = in + ((size_t)lane * 256 + cc) * 12;
    const float* wp = w + ((size_t)co0 * 256 + cc) * 9;

#pragma unroll 2
    for (int ci = 0; ci < 16; ++ci) {
        float p[12];
        const float4* p4 = (const float4*)(ip + ci * 12);
        float4 a0 = p4[0], a1 = p4[1], a2 = p4[2];
        p[0] = a0.x; p[1] = a0.y; p[2]  = a0.z; p[3]  = a0.w;
        p[4] = a1.x; p[5] = a1.y; p[6]  = a1.z; p[7]  = a1.w;
        p[8] = a2.x; p[9] = a2.y; p[10] = a2.z; p[11] = a2.w;
#pragma unroll
        for (int j = 0; j < 4; ++j) {
            const float* wj = wp + ((size_t)j * 256 + ci) * 9;
            float wr[9];
#pragma unroll
            for (int k = 0; k < 9; ++k) wr[k] = wj[k];
#pragma unroll
            for (int oh = 0; oh < 4; ++oh)
#pragma unroll
                for (int ow = 0; ow < 3; ++ow)
#pragma unroll
                    for (int kh = 0; kh < 3; ++kh) {
                        int ih = oh - 1 + kh;
                        if (ih < 0 || ih >= 4) continue;
#pragma unroll
                        for (int kw = 0; kw < 3; ++kw) {
                            int iw = ow - 1 + kw;
                            if (iw < 0 || iw >= 3) continue;
                            acc[j][oh * 3 + ow] =
                                fmaf(p[ih * 3 + iw], wr[kh * 3 + kw], acc[j][oh * 3 + ow]);
                        }
                    }
        }
    }

    float* pb = pbuf + ((size_t)(cic * 64 + lane) * 256 + co0) * 12;
#pragma unroll
    for (int j = 0; j < 4; ++j) {
        float4* o4 = (float4*)(pb + j * 12);
        o4[0] = make_float4(acc[j][0], acc[j][1], acc[j][2],  acc[j][3]);
        o4[1] = make_float4(acc[j][4], acc[j][5], acc[j][6],  acc[j][7]);
        o4[2] = make_float4(acc[j][8], acc[j][9], acc[j][10], acc[j][11]);
    }
}

// ---------------------------------------------------------------------------
// Layer 5 conv: (128,8,6)->(256,4,3), K=4,S=2,pad=1. Same scheme, CICH=8.
// ---------------------------------------------------------------------------
__global__ __launch_bounds__(256) void conv_l5(const float* __restrict__ in,
                                               const float* __restrict__ w,
                                               float* __restrict__ pbuf)
{
    int t    = threadIdx.x;
    int gw   = blockIdx.x * 4 + (t >> 6);   // 0..1023
    int lane = t & 63;                      // = n
    int cic  = gw >> 6;                     // 0..15
    int cog  = gw & 63;                     // 0..63
    int cc   = cic * 8;
    int co0  = cog * 4;

    float acc[4][12];
#pragma unroll
    for (int j = 0; j < 4; ++j)
#pragma unroll
        for (int p = 0; p < 12; ++p) acc[j][p] = 0.f;

    const float* ip = in + ((size_t)lane * 128 + cc) * 48;
    const float* wp = w + ((size_t)co0 * 128 + cc) * 16;

#pragma unroll 1
    for (int ci = 0; ci < 8; ++ci) {
        float p[48];
        const float4* p4 = (const float4*)(ip + ci * 48);
#pragma unroll
        for (int q = 0; q < 12; ++q) {
            float4 a = p4[q];
            p[q * 4 + 0] = a.x; p[q * 4 + 1] = a.y; p[q * 4 + 2] = a.z; p[q * 4 + 3] = a.w;
        }
#pragma unroll
        for (int j = 0; j < 4; ++j) {
            const float* wj = wp + ((size_t)j * 128 + ci) * 16;
            float wr[16];
#pragma unroll
            for (int k = 0; k < 16; ++k) wr[k] = wj[k];
#pragma unroll
            for (int oh = 0; oh < 4; ++oh)
#pragma unroll
                for (int ow = 0; ow < 3; ++ow) {
                    int ih0 = 2 * oh - 1, iw0 = 2 * ow - 1;
#pragma unroll
                    for (int kh = 0; kh < 4; ++kh) {
                        int ih = ih0 + kh;
                        if (ih < 0 || ih >= 8) continue;
#pragma unroll
                        for (int kw = 0; kw < 4; ++kw) {
                            int iw = iw0 + kw;
                            if (iw < 0 || iw >= 6) continue;
                            acc[j][oh * 3 + ow] =
                                fmaf(p[ih * 6 + iw], wr[kh * 4 + kw], acc[j][oh * 3 + ow]);
                        }
                    }
                }
        }
    }

    float* pb = pbuf + ((size_t)(cic * 64 + lane) * 256 + co0) * 12;
#pragma unroll
    for (int j = 0; j < 4; ++j) {
        float4* o4 = (float4*)(pb + j * 12);
        o4[0] = make_float4(acc[j][0], acc[j][1], acc[j][2],  acc[j][3]);
        o4[1] = make_float4(acc[j][4], acc[j][5], acc[j][6],  acc[j][7]);
        o4[2] = make_float4(acc[j][8], acc[j][9], acc[j][10], acc[j][11]);
    }
}

// ---------------------------------------------------------------------------
// Reduce 16 partial chunks + instance norm over 12 px + relu.
// pbuf layout: [cic(16)][n(64)][co(256)][px(12)]; out: [n][co][px].
// ---------------------------------------------------------------------------
__global__ __launch_bounds__(256) void reduce_norm12(const float* __restrict__ pbuf,
                                                     float* __restrict__ out)
{
    int g  = blockIdx.x * blockDim.x + threadIdx.x;   // 16384 threads
    int co = g & 255;
    int n  = g >> 8;
    float s[12];
#pragma unroll
    for (int p = 0; p < 12; ++p) s[p] = 0.f;
#pragma unroll 1
    for (int c = 0; c < 16; ++c) {
        const float4* p4 = (const float4*)(pbuf + ((size_t)(c * 64 + n) * 256 + co) * 12);
        float4 a = p4[0], b = p4[1], d = p4[2];
        s[0] += a.x; s[1] += a.y; s[2]  += a.z; s[3]  += a.w;
        s[4] += b.x; s[5] += b.y; s[6]  += b.z; s[7]  += b.w;
        s[8] += d.x; s[9] += d.y; s[10] += d.z; s[11] += d.w;
    }
    float m = 0.f;
#pragma unroll
    for (int p = 0; p < 12; ++p) m += s[p];
    m *= (1.f / 12.f);
    float q = 0.f;
#pragma unroll
    for (int p = 0; p < 12; ++p) { float d = s[p] - m; q += d * d; }
    q *= (1.f / 12.f);
    float r = rsqrtf(q + EPS);
    float* op = out + ((size_t)n * 256 + co) * 12;
    float4* o4 = (float4*)op;
    float y[12];
#pragma unroll
    for (int p = 0; p < 12; ++p) y[p] = fmaxf((s[p] - m) * r, 0.f);
    o4[0] = make_float4(y[0], y[1], y[2],  y[3]);
    o4[1] = make_float4(y[4], y[5], y[6],  y[7]);
    o4[2] = make_float4(y[8], y[9], y[10], y[11]);
}

// ---------------------------------------------------------------------------
// Instance norm (block variant, large planes)
// ---------------------------------------------------------------------------
__global__ void inorm_block(float* __restrict__ data, int HW, int relu)
{
    float* p = data + (size_t)blockIdx.x * HW;
    __shared__ float ssum[256], ssq[256];
    float s = 0.f, q = 0.f;
    for (int i = threadIdx.x; i < HW; i += blockDim.x) {
        float v = p[i]; s += v; q += v * v;
    }
    ssum[threadIdx.x] = s; ssq[threadIdx.x] = q;
    __syncthreads();
    for (int off = blockDim.x / 2; off > 0; off >>= 1) {
        if ((int)threadIdx.x < off) {
            ssum[threadIdx.x] += ssum[threadIdx.x + off];
            ssq[threadIdx.x]  += ssq[threadIdx.x + off];
        }
        __syncthreads();
    }
    float m = ssum[0] / (float)HW;
    float v = ssq[0] / (float)HW - m * m;
    float r = rsqrtf(v + EPS);
    for (int i = threadIdx.x; i < HW; i += blockDim.x) {
        float y = (p[i] - m) * r;
        if (relu) y = fmaxf(y, 0.f);
        p[i] = y;
    }
}

// Instance norm (wave variant, small planes) — still used for L3, L4
__global__ void inorm_wave(float* __restrict__ data, int nplanes, int HW, int relu)
{
    int gid  = blockIdx.x * blockDim.x + threadIdx.x;
    int wave = gid >> 6;
    int lane = gid & 63;
    if (wave >= nplanes) return;
    float* p = data + (size_t)wave * HW;
    float s = 0.f, q = 0.f;
    for (int i = lane; i < HW; i += 64) {
        float v = p[i]; s += v; q += v * v;
    }
    for (int m = 32; m >= 1; m >>= 1) {
        s += __shfl_xor(s, m);
        q += __shfl_xor(q, m);
    }
    float mean = s / (float)HW;
    float var  = q / (float)HW - mean * mean;
    float r = rsqrtf(var + EPS);
    for (int i = lane; i < HW; i += 64) {
        float y = (p[i] - mean) * r;
        if (relu) y = fmaxf(y, 0.f);
        p[i] = y;
    }
}

// maxpool (64,256,4,3) -> (64,512)
__global__ void pool_kernel(const float* __restrict__ in, float* __restrict__ out)
{
    int idx = blockIdx.x * blockDim.x + threadIdx.x;
    if (idx >= 64 * 512) return;
    int f = idx & 511;
    int n = idx >> 9;
    int c = f >> 1;
    int h = f & 1;
    const float* p = in + (((size_t)n * 256 + c) * 4 + h * 2) * 3;
    out[idx] = fmaxf(fmaxf(p[0], p[1]), fmaxf(p[3], p[4]));
}

__global__ void fc1_kernel(const float* __restrict__ in, const float* __restrict__ w,
                           const float* __restrict__ b, float* __restrict__ out)
{
    int idx = blockIdx.x * blockDim.x + threadIdx.x;
    if (idx >= 64 * 128) return;
    int j = idx & 127;
    int n = idx >> 7;
    const float* x  = in + n * 512;
    const float* wr = w + j * 512;
    float acc = b[j];
    for (int f = 0; f < 512; ++f) acc = fmaf(x[f], wr[f], acc);
    out[idx] = fmaxf(acc, 0.f);
}

__global__ void fc2_kernel(const float* __restrict__ in, const float* __restrict__ w,
                           const float* __restrict__ b, float* __restrict__ out)
{
    int idx = blockIdx.x * blockDim.x + threadIdx.x;
    if (idx >= 64 * 50) return;
    int k = idx % 50;
    int n = idx / 50;
    const float* x  = in + n * 128;
    const float* wr = w + k * 128;
    float acc = b[k];
    for (int f = 0; f < 128; ++f) acc = fmaf(x[f], wr[f], acc);
    out[idx] = tanhf(acc);
}

__global__ void loss_kernel(const float* __restrict__ pts, float* __restrict__ out)
{
    __shared__ float acc[4][64];
    int n = threadIdx.x;
    float rx = 0.f, ry = 0.f, cx = 0.f, cy = 0.f;
    {
        const float* g = pts + n * 50;
        for (int r = 0; r < 5; ++r)
            for (int j = 0; j < 3; ++j)
                for (int d = 0; d < 2; ++d) {
                    float a0 = g[(r * 5 + j) * 2 + d];
                    float a1 = g[(r * 5 + j + 1) * 2 + d];
                    float a2 = g[(r * 5 + j + 2) * 2 + d];
                    float d0 = (a1 - a0) * (a1 - a0);
                    float d1 = (a2 - a1) * (a2 - a1);
                    float t = fmaxf(0.08f, fabsf(d1 - d0));
                    if (d == 0) rx += t; else ry += t;
                }
        for (int r = 0; r < 5; ++r)
            for (int j = 0; j < 3; ++j)
                for (int d = 0; d < 2; ++d) {
                    float a0 = g[(j * 5 + r) * 2 + d];
                    float a1 = g[((j + 1) * 5 + r) * 2 + d];
                    float a2 = g[((j + 2) * 5 + r) * 2 + d];
                    float d0 = (a1 - a0) * (a1 - a0);
                    float d1 = (a2 - a1) * (a2 - a1);
                    float t = fmaxf(0.08f, fabsf(d1 - d0));
                    if (d == 0) cx += t; else cy += t;
                }
    }
    acc[0][n] = rx; acc[1][n] = ry; acc[2][n] = cx; acc[3][n] = cy;
    __syncthreads();
    if (n == 0) {
        float s0 = 0.f, s1 = 0.f, s2 = 0.f, s3 = 0.f;
        for (int i = 0; i < 64; ++i) {
            s0 += acc[0][i]; s1 += acc[1][i]; s2 += acc[2][i]; s3 += acc[3][i];
        }
        float inv = 1.0f / (64.0f * 15.0f);
        out[3200] = s0 * inv;
        out[3201] = s1 * inv;
        out[3202] = s2 * inv;
        out[3203] = s3 * inv;
        const float* g = pts;
        float rg = 0.f, cg = 0.f;
        for (int r = 0; r < 5; ++r)
            for (int j = 0; j < 3; ++j) {
                float x0 = g[(r * 5 + j) * 2],     y0 = g[(r * 5 + j) * 2 + 1];
                float x1 = g[(r * 5 + j + 1) * 2], y1 = g[(r * 5 + j + 1) * 2 + 1];
                float x2 = g[(r * 5 + j + 2) * 2], y2 = g[(r * 5 + j + 2) * 2 + 1];
                rg += fabsf((y1 - y0) * (x1 - x2) - (y1 - y2) * (x1 - x0));
            }
        for (int r = 0; r < 5; ++r)
            for (int j = 0; j < 3; ++j) {
                float x0 = g[(j * 5 + r) * 2],       y0 = g[(j * 5 + r) * 2 + 1];
                float x1 = g[((j + 1) * 5 + r) * 2], y1 = g[((j + 1) * 5 + r) * 2 + 1];
                float x2 = g[((j + 2) * 5 + r) * 2], y2 = g[((j + 2) * 5 + r) * 2 + 1];
                cg += fabsf((y1 - y0) * (x1 - x2) - (y1 - y2) * (x1 - x0));
            }
        out[3204] = fmaxf(rg, 0.02f);
        out[3205] = fmaxf(cg, 0.02f);
    }
}

extern "C" void kernel_launch(void* const* d_in, const int* in_sizes, int n_in,
                              void* d_out, int out_size, void* d_ws, size_t ws_size,
                              hipStream_t stream)
{
    const float* x = (const float*)d_in[0];
    const float* w[8], *bia[8];
    for (int i = 0; i < 6; ++i) { w[i] = (const float*)d_in[1 + 2 * i]; bia[i] = (const float*)d_in[2 + 2 * i]; }
    w[6] = (const float*)d_in[13]; bia[6] = (const float*)d_in[14];
    w[7] = (const float*)d_in[15]; bia[7] = (const float*)d_in[16];
    const float* fc1_w = (const float*)d_in[17];
    const float* fc1_b = (const float*)d_in[18];
    const float* fc2_w = (const float*)d_in[19];
    const float* fc2_b = (const float*)d_in[20];
    float* out = (float*)d_out;

    float* A      = (float*)d_ws;                 // ping (6,291,456 floats)
    float* Bf     = A + 6291456;                  // pong (3,145,728 floats)
    float* pooled = Bf + 3145728;
    float* fc1o   = pooled + 32768;
    float* pbuf   = A + 1048576;                  // 3,145,728 floats of partials
                                                  // (disjoint from live inputs/outputs of L5-L7)

    const int N = 64;
    const float* cur = x;
    float* bufs[2] = {A, Bf};

    // ---- L0: (5,256,192) -> (8,128,96), conv+relu then norm ----
    {
        float* dst = bufs[0];
        conv42<5, 8><<<3072, 256, 0, stream>>>(cur, w[0], bia[0], dst, N, 256, 192, 8, 128, 96, 1);
        inorm_block<<<N * 8, 256, 0, stream>>>(dst, 128 * 96, 0);
        cur = dst;
    }
    // ---- L1: (8,128,96) -> (16,64,48) ----
    {
        float* dst = bufs[1];
        conv42<8, 16><<<768, 256, 0, stream>>>(cur, w[1], bia[1], dst, N, 128, 96, 16, 64, 48, 0);
        inorm_block<<<N * 16, 256, 0, stream>>>(dst, 64 * 48, 1);
        cur = dst;
    }
    // ---- L2: (16,64,48) -> (32,32,24) ----
    {
        float* dst = bufs[0];
        conv42<16, 16><<<384, 256, 0, stream>>>(cur, w[2], bia[2], dst, N, 64, 48, 32, 32, 24, 0);
        inorm_block<<<N * 32, 256, 0, stream>>>(dst, 32 * 24, 1);
        cur = dst;
    }
    // ---- L3: (32,32,24) -> (64,16,12) ----
    {
        float* dst = bufs[1];
        conv42<32, 8><<<512, 192, 0, stream>>>(cur, w[3], bia[3], dst, N, 32, 24, 64, 16, 12, 0);
        inorm_wave<<<(N * 64 * 64 + 255) / 256, 256, 0, stream>>>(dst, N * 64, 192, 1);
        cur = dst;
    }
    // ---- L4: (64,16,12) -> (128,8,6) ----
    {
        float* dst = bufs[0];
        conv_lds<64, 16, 12, 128, 4, 2, 16, 4, 8><<<512, 192, 0, stream>>>(cur, w[4], bia[4], dst, 0);
        inorm_wave<<<(N * 128 * 64 + 255) / 256, 256, 0, stream>>>(dst, N * 128, 48, 1);
        cur = dst;
    }
    // ---- L5: (128,8,6) -> (256,4,3). lane-n kernel + fused reduce/norm/relu ----
    {
        float* dst = bufs[1];
        conv_l5<<<256, 256, 0, stream>>>(cur, w[5], pbuf);
        reduce_norm12<<<64, 256, 0, stream>>>(pbuf, dst);
        cur = dst;
    }
    // ---- L6, L7: (256,4,3) -> (256,4,3), K=3 s=1 ----
    for (int i = 6; i < 8; ++i) {
        float* dst = bufs[i & 1];
        conv_l67<<<256, 256, 0, stream>>>(cur, w[i], pbuf);
        reduce_norm12<<<64, 256, 0, stream>>>(pbuf, dst);
        cur = dst;
    }

    pool_kernel<<<(64 * 512 + 255) / 256, 256, 0, stream>>>(cur, pooled);
    fc1_kernel<<<(64 * 128 + 255) / 256, 256, 0, stream>>>(pooled, fc1_w, fc1_b, fc1o);
    fc2_kernel<<<(64 * 50 + 255) / 256, 256, 0, stream>>>(fc1o, fc2_w, fc2_b, out);
    loss_kernel<<<1, 64, 0, stream>>>(out, out);
}

// Round 4
// 542.966 us; speedup vs baseline: 4.9994x; 1.1163x over previous
//
#include <hip/hip_runtime.h>
#include <hip/hip_bf16.h>
#include <math.h>

#define EPS 1e-5f

// ---------------------------------------------------------------------------
// Kernel A: K=4, stride=2, pad=1 conv. One thread per output pixel, CPT output
// channels per thread. Block weights staged in LDS. (Layers 0-3.)
// ---------------------------------------------------------------------------
template<int CIN, int CPT>
__global__ void conv42(const float* __restrict__ in, const float* __restrict__ w,
                       const float* __restrict__ bias, float* __restrict__ out,
                       int N, int H, int W, int COUT, int OH, int OW, int relu)
{
    const int NPX = OH * OW;
    const int PXB = NPX / blockDim.x;
    const int NCG = COUT / CPT;

    int bx  = blockIdx.x;
    int pxb = bx % PXB;
    int cg  = (bx / PXB) % NCG;
    int n   = bx / (PXB * NCG);
    int tid = threadIdx.x;

    __shared__ float sW[CPT * CIN * 16];
    for (int i = tid; i < CPT * CIN * 16; i += blockDim.x) {
        int ci = i / (CPT * 16);
        int r  = i % (CPT * 16);
        int j  = r / 16;
        int k  = r % 16;
        sW[i] = w[((size_t)(cg * CPT + j) * CIN + ci) * 16 + k];
    }
    __syncthreads();

    int px = pxb * blockDim.x + tid;
    int oh = px / OW, ow = px % OW;
    int ih0 = oh * 2 - 1, iw0 = ow * 2 - 1;

    float acc[CPT];
#pragma unroll
    for (int j = 0; j < CPT; ++j) acc[j] = bias[cg * CPT + j];

    const float* ib = in + (size_t)n * CIN * H * W;
    for (int ci = 0; ci < CIN; ++ci) {
        float p[16];
        const float* plane = ib + (size_t)ci * H * W;
#pragma unroll
        for (int kh = 0; kh < 4; ++kh) {
            int ih = ih0 + kh;
            bool vr = (unsigned)ih < (unsigned)H;
            const float* row = plane + (size_t)ih * W;
#pragma unroll
            for (int kw = 0; kw < 4; ++kw) {
                int iw = iw0 + kw;
                bool v = vr && ((unsigned)iw < (unsigned)W);
                p[kh * 4 + kw] = v ? row[iw] : 0.f;
            }
        }
        const float* wp = sW + ci * CPT * 16;
#pragma unroll
        for (int j = 0; j < CPT; ++j) {
            const float* wj = wp + j * 16;
#pragma unroll
            for (int k = 0; k < 16; ++k) acc[j] = fmaf(p[k], wj[k], acc[j]);
        }
    }

#pragma unroll
    for (int j = 0; j < CPT; ++j) {
        float v = acc[j];
        if (relu) v = fmaxf(v, 0.f);
        out[((size_t)(n * COUT + cg * CPT + j) * OH + oh) * OW + ow] = v;
    }
}

// ---------------------------------------------------------------------------
// Layer 4 conv: (64,16,12)->(128,8,6), K=4,S=2,pad=1.
// Input TRANSPOSED [ci][px(192)][n(64)] so lane=n loads are coalesced 256B.
// wave = (co-pair, ci-chunk of 8, oh-half). Weights wave-uniform -> SGPR.
// Writes partials (bias cancels under instance norm).
// ---------------------------------------------------------------------------
__global__ __launch_bounds__(256) void conv_l4(const float* __restrict__ in_t,
                                               const float* __restrict__ w,
                                               float* __restrict__ pbuf)
{
    int t    = threadIdx.x;
    int lane = t & 63;                      // = n
    int gw   = __builtin_amdgcn_readfirstlane(blockIdx.x * 4 + (t >> 6)); // 0..1023
    int cog  = gw & 63;
    int cic  = (gw >> 6) & 7;
    int half = gw >> 9;
    int cc   = cic * 8;
    int co0  = cog * 2;
    int oh0  = half * 4;

    float acc[2][24];
#pragma unroll
    for (int j = 0; j < 2; ++j)
#pragma unroll
        for (int p = 0; p < 24; ++p) acc[j][p] = 0.f;

    const float* wp = w + ((size_t)co0 * 64 + cc) * 16;

#pragma unroll 1
    for (int ci = 0; ci < 8; ++ci) {
        const float* pl = in_t + (size_t)(cc + ci) * 192 * 64 + lane;
        float wr[2][16];
#pragma unroll
        for (int k = 0; k < 16; ++k) {
            wr[0][k] = wp[(0 * 64 + ci) * 16 + k];
            wr[1][k] = wp[(1 * 64 + ci) * 16 + k];
        }
#pragma unroll
        for (int kh = 0; kh < 4; ++kh) {
            float p[4][12];
#pragma unroll
            for (int o = 0; o < 4; ++o) {
                int ih = 2 * (oh0 + o) - 1 + kh;
                if ((unsigned)ih < 16u) {
#pragma unroll
                    for (int c = 0; c < 12; ++c)
                        p[o][c] = pl[(size_t)(ih * 12 + c) * 64];
                } else {
#pragma unroll
                    for (int c = 0; c < 12; ++c) p[o][c] = 0.f;
                }
            }
#pragma unroll
            for (int o = 0; o < 4; ++o)
#pragma unroll
                for (int ow = 0; ow < 6; ++ow) {
#pragma unroll
                    for (int kw = 0; kw < 4; ++kw) {
                        int iw = 2 * ow - 1 + kw;
                        if (iw < 0 || iw >= 12) continue;
                        float pv = p[o][iw];
                        acc[0][o * 6 + ow] = fmaf(pv, wr[0][kh * 4 + kw], acc[0][o * 6 + ow]);
                        acc[1][o * 6 + ow] = fmaf(pv, wr[1][kh * 4 + kw], acc[1][o * 6 + ow]);
                    }
                }
        }
    }

    // pbuf[cic(8)][n(64)][co(128)][px(48)], this thread covers px oh0*6 .. +23
    float* pb = pbuf + ((size_t)(cic * 64 + lane) * 128 + co0) * 48 + oh0 * 6;
#pragma unroll
    for (int j = 0; j < 2; ++j) {
        float4* o4 = (float4*)(pb + j * 48);
#pragma unroll
        for (int q = 0; q < 6; ++q)
            o4[q] = make_float4(acc[j][q * 4 + 0], acc[j][q * 4 + 1],
                                acc[j][q * 4 + 2], acc[j][q * 4 + 3]);
    }
}

// ---------------------------------------------------------------------------
// Reduce 8 partial chunks + instance norm over 48 px + relu.
// pbuf: [cic(8)][n(64)][co(128)][px(48)]; out: [n][co][48] standard.
// ---------------------------------------------------------------------------
__global__ __launch_bounds__(256) void reduce_norm48(const float* __restrict__ pbuf,
                                                     float* __restrict__ out)
{
    int g  = blockIdx.x * blockDim.x + threadIdx.x;   // 8192 threads
    int co = g & 127;
    int n  = g >> 7;
    float s[48];
#pragma unroll
    for (int p = 0; p < 48; ++p) s[p] = 0.f;
#pragma unroll 1
    for (int c = 0; c < 8; ++c) {
        const float4* p4 = (const float4*)(pbuf + ((size_t)(c * 64 + n) * 128 + co) * 48);
#pragma unroll
        for (int q = 0; q < 12; ++q) {
            float4 a = p4[q];
            s[q * 4 + 0] += a.x; s[q * 4 + 1] += a.y;
            s[q * 4 + 2] += a.z; s[q * 4 + 3] += a.w;
        }
    }
    float m = 0.f;
#pragma unroll
    for (int p = 0; p < 48; ++p) m += s[p];
    m *= (1.f / 48.f);
    float q = 0.f;
#pragma unroll
    for (int p = 0; p < 48; ++p) { float d = s[p] - m; q += d * d; }
    q *= (1.f / 48.f);
    float r = rsqrtf(q + EPS);
    float4* o4 = (float4*)(out + ((size_t)n * 128 + co) * 48);
#pragma unroll
    for (int qq = 0; qq < 12; ++qq) {
        float4 v;
        v.x = fmaxf((s[qq * 4 + 0] - m) * r, 0.f);
        v.y = fmaxf((s[qq * 4 + 1] - m) * r, 0.f);
        v.z = fmaxf((s[qq * 4 + 2] - m) * r, 0.f);
        v.w = fmaxf((s[qq * 4 + 3] - m) * r, 0.f);
        o4[qq] = v;
    }
}

// ---------------------------------------------------------------------------
// Layer 6/7 conv: (256,4,3)->(256,4,3), K=3,S=1,pad=1. lane=n scheme.
// ---------------------------------------------------------------------------
__global__ __launch_bounds__(256) void conv_l67(const float* __restrict__ in,
                                                const float* __restrict__ w,
                                                float* __restrict__ pbuf)
{
    int t    = threadIdx.x;
    int gw   = __builtin_amdgcn_readfirstlane(blockIdx.x * 4 + (t >> 6));
    int lane = t & 63;
    int cic  = gw >> 6;
    int cog  = gw & 63;
    int cc   = cic * 16;
    int co0  = cog * 4;

    float acc[4][12];
#pragma unroll
    for (int j = 0; j < 4; ++j)
#pragma unroll
        for (int p = 0; p < 12; ++p) acc[j][p] = 0.f;

    const float* ip = in + ((size_t)lane * 256 + cc) * 12;
    const float* wp = w + ((size_t)co0 * 256 + cc) * 9;

#pragma unroll 2
    for (int ci = 0; ci < 16; ++ci) {
        float p[12];
        const float4* p4 = (const float4*)(ip + ci * 12);
        float4 a0 = p4[0], a1 = p4[1], a2 = p4[2];
        p[0] = a0.x; p[1] = a0.y; p[2]  = a0.z; p[3]  = a0.w;
        p[4] = a1.x; p[5] = a1.y; p[6]  = a1.z; p[7]  = a1.w;
        p[8] = a2.x; p[9] = a2.y; p[10] = a2.z; p[11] = a2.w;
#pragma unroll
        for (int j = 0; j < 4; ++j) {
            const float* wj = wp + ((size_t)j * 256 + ci) * 9;
            float wr[9];
#pragma unroll
            for (int k = 0; k < 9; ++k) wr[k] = wj[k];
#pragma unroll
            for (int oh = 0; oh < 4; ++oh)
#pragma unroll
                for (int ow = 0; ow < 3; ++ow)
#pragma unroll
                    for (int kh = 0; kh < 3; ++kh) {
                        int ih = oh - 1 + kh;
                        if (ih < 0 || ih >= 4) continue;
#pragma unroll
                        for (int kw = 0; kw < 3; ++kw) {
                            int iw = ow - 1 + kw;
                            if (iw < 0 || iw >= 3) continue;
                            acc[j][oh * 3 + ow] =
                                fmaf(p[ih * 3 + iw], wr[kh * 3 + kw], acc[j][oh * 3 + ow]);
                        }
                    }
        }
    }

    float* pb = pbuf + ((size_t)(cic * 64 + lane) * 256 + co0) * 12;
#pragma unroll
    for (int j = 0; j < 4; ++j) {
        float4* o4 = (float4*)(pb + j * 12);
        o4[0] = make_float4(acc[j][0], acc[j][1], acc[j][2],  acc[j][3]);
        o4[1] = make_float4(acc[j][4], acc[j][5], acc[j][6],  acc[j][7]);
        o4[2] = make_float4(acc[j][8], acc[j][9], acc[j][10], acc[j][11]);
    }
}

// ---------------------------------------------------------------------------
// Layer 5 conv: (128,8,6)->(256,4,3), K=4,S=2,pad=1. lane=n scheme.
// ---------------------------------------------------------------------------
__global__ __launch_bounds__(256) void conv_l5(const float* __restrict__ in,
                                               const float* __restrict__ w,
                                               float* __restrict__ pbuf)
{
    int t    = threadIdx.x;
    int gw   = __builtin_amdgcn_readfirstlane(blockIdx.x * 4 + (t >> 6));
    int lane = t & 63;
    int cic  = gw >> 6;
    int cog  = gw & 63;
    int cc   = cic * 8;
    int co0  = cog * 4;

    float acc[4][12];
#pragma unroll
    for (int j = 0; j < 4; ++j)
#pragma unroll
        for (int p = 0; p < 12; ++p) acc[j][p] = 0.f;

    const float* ip = in + ((size_t)lane * 128 + cc) * 48;
    const float* wp = w + ((size_t)co0 * 128 + cc) * 16;

#pragma unroll 1
    for (int ci = 0; ci < 8; ++ci) {
        float p[48];
        const float4* p4 = (const float4*)(ip + ci * 48);
#pragma unroll
        for (int q = 0; q < 12; ++q) {
            float4 a = p4[q];
            p[q * 4 + 0] = a.x; p[q * 4 + 1] = a.y; p[q * 4 + 2] = a.z; p[q * 4 + 3] = a.w;
        }
#pragma unroll
        for (int j = 0; j < 4; ++j) {
            const float* wj = wp + ((size_t)j * 128 + ci) * 16;
            float wr[16];
#pragma unroll
            for (int k = 0; k < 16; ++k) wr[k] = wj[k];
#pragma unroll
            for (int oh = 0; oh < 4; ++oh)
#pragma unroll
                for (int ow = 0; ow < 3; ++ow) {
                    int ih0 = 2 * oh - 1, iw0 = 2 * ow - 1;
#pragma unroll
                    for (int kh = 0; kh < 4; ++kh) {
                        int ih = ih0 + kh;
                        if (ih < 0 || ih >= 8) continue;
#pragma unroll
                        for (int kw = 0; kw < 4; ++kw) {
                            int iw = iw0 + kw;
                            if (iw < 0 || iw >= 6) continue;
                            acc[j][oh * 3 + ow] =
                                fmaf(p[ih * 6 + iw], wr[kh * 4 + kw], acc[j][oh * 3 + ow]);
                        }
                    }
                }
        }
    }

    float* pb = pbuf + ((size_t)(cic * 64 + lane) * 256 + co0) * 12;
#pragma unroll
    for (int j = 0; j < 4; ++j) {
        float4* o4 = (float4*)(pb + j * 12);
        o4[0] = make_float4(acc[j][0], acc[j][1], acc[j][2],  acc[j][3]);
        o4[1] = make_float4(acc[j][4], acc[j][5], acc[j][6],  acc[j][7]);
        o4[2] = make_float4(acc[j][8], acc[j][9], acc[j][10], acc[j][11]);
    }
}

// ---------------------------------------------------------------------------
// Reduce 16 partial chunks + instance norm over 12 px + relu (L5-L7).
// ---------------------------------------------------------------------------
__global__ __launch_bounds__(256) void reduce_norm12(const float* __restrict__ pbuf,
                                                     float* __restrict__ out)
{
    int g  = blockIdx.x * blockDim.x + threadIdx.x;   // 16384 threads
    int co = g & 255;
    int n  = g >> 8;
    float s[12];
#pragma unroll
    for (int p = 0; p < 12; ++p) s[p] = 0.f;
#pragma unroll 1
    for (int c = 0; c < 16; ++c) {
        const float4* p4 = (const float4*)(pbuf + ((size_t)(c * 64 + n) * 256 + co) * 12);
        float4 a = p4[0], b = p4[1], d = p4[2];
        s[0] += a.x; s[1] += a.y; s[2]  += a.z; s[3]  += a.w;
        s[4] += b.x; s[5] += b.y; s[6]  += b.z; s[7]  += b.w;
        s[8] += d.x; s[9] += d.y; s[10] += d.z; s[11] += d.w;
    }
    float m = 0.f;
#pragma unroll
    for (int p = 0; p < 12; ++p) m += s[p];
    m *= (1.f / 12.f);
    float q = 0.f;
#pragma unroll
    for (int p = 0; p < 12; ++p) { float d = s[p] - m; q += d * d; }
    q *= (1.f / 12.f);
    float r = rsqrtf(q + EPS);
    float* op = out + ((size_t)n * 256 + co) * 12;
    float4* o4 = (float4*)op;
    float y[12];
#pragma unroll
    for (int p = 0; p < 12; ++p) y[p] = fmaxf((s[p] - m) * r, 0.f);
    o4[0] = make_float4(y[0], y[1], y[2],  y[3]);
    o4[1] = make_float4(y[4], y[5], y[6],  y[7]);
    o4[2] = make_float4(y[8], y[9], y[10], y[11]);
}

// ---------------------------------------------------------------------------
// Instance norm (block variant, large planes)
// ---------------------------------------------------------------------------
__global__ void inorm_block(float* __restrict__ data, int HW, int relu)
{
    float* p = data + (size_t)blockIdx.x * HW;
    __shared__ float ssum[256], ssq[256];
    float s = 0.f, q = 0.f;
    for (int i = threadIdx.x; i < HW; i += blockDim.x) {
        float v = p[i]; s += v; q += v * v;
    }
    ssum[threadIdx.x] = s; ssq[threadIdx.x] = q;
    __syncthreads();
    for (int off = blockDim.x / 2; off > 0; off >>= 1) {
        if ((int)threadIdx.x < off) {
            ssum[threadIdx.x] += ssum[threadIdx.x + off];
            ssq[threadIdx.x]  += ssq[threadIdx.x + off];
        }
        __syncthreads();
    }
    float m = ssum[0] / (float)HW;
    float v = ssq[0] / (float)HW - m * m;
    float r = rsqrtf(v + EPS);
    for (int i = threadIdx.x; i < HW; i += blockDim.x) {
        float y = (p[i] - m) * r;
        if (relu) y = fmaxf(y, 0.f);
        p[i] = y;
    }
}

// Instance norm, wave variant, TRANSPOSED output [c][px][n] (used after L3).
__global__ void inorm_wave_T(const float* __restrict__ src, float* __restrict__ dst_t,
                             int nplanes, int C, int HW, int relu)
{
    int gid  = blockIdx.x * blockDim.x + threadIdx.x;
    int wave = gid >> 6;
    int lane = gid & 63;
    if (wave >= nplanes) return;
    int n = wave / C, c = wave % C;
    const float* p = src + (size_t)wave * HW;
    float s = 0.f, q = 0.f;
    for (int i = lane; i < HW; i += 64) {
        float v = p[i]; s += v; q += v * v;
    }
    for (int m = 32; m >= 1; m >>= 1) {
        s += __shfl_xor(s, m);
        q += __shfl_xor(q, m);
    }
    float mean = s / (float)HW;
    float var  = q / (float)HW - mean * mean;
    float r = rsqrtf(var + EPS);
    for (int i = lane; i < HW; i += 64) {
        float y = (p[i] - mean) * r;
        if (relu) y = fmaxf(y, 0.f);
        dst_t[((size_t)c * HW + i) * 64 + n] = y;
    }
}

// Instance norm (wave variant, standard layout) — still used for L3? no: L3 uses _T.
__global__ void inorm_wave(float* __restrict__ data, int nplanes, int HW, int relu)
{
    int gid  = blockIdx.x * blockDim.x + threadIdx.x;
    int wave = gid >> 6;
    int lane = gid & 63;
    if (wave >= nplanes) return;
    float* p = data + (size_t)wave * HW;
    float s = 0.f, q = 0.f;
    for (int i = lane; i < HW; i += 64) {
        float v = p[i]; s += v; q += v * v;
    }
    for (int m = 32; m >= 1; m >>= 1) {
        s += __shfl_xor(s, m);
        q += __shfl_xor(q, m);
    }
    float mean = s / (float)HW;
    float var  = q / (float)HW - mean * mean;
    float r = rsqrtf(var + EPS);
    for (int i = lane; i < HW; i += 64) {
        float y = (p[i] - mean) * r;
        if (relu) y = fmaxf(y, 0.f);
        p[i] = y;
    }
}

// maxpool (64,256,4,3) -> (64,512)
__global__ void pool_kernel(const float* __restrict__ in, float* __restrict__ out)
{
    int idx = blockIdx.x * blockDim.x + threadIdx.x;
    if (idx >= 64 * 512) return;
    int f = idx & 511;
    int n = idx >> 9;
    int c = f >> 1;
    int h = f & 1;
    const float* p = in + (((size_t)n * 256 + c) * 4 + h * 2) * 3;
    out[idx] = fmaxf(fmaxf(p[0], p[1]), fmaxf(p[3], p[4]));
}

__global__ void fc1_kernel(const float* __restrict__ in, const float* __restrict__ w,
                           const float* __restrict__ b, float* __restrict__ out)
{
    int idx = blockIdx.x * blockDim.x + threadIdx.x;
    if (idx >= 64 * 128) return;
    int j = idx & 127;
    int n = idx >> 7;
    const float* x  = in + n * 512;
    const float* wr = w + j * 512;
    float acc = b[j];
    for (int f = 0; f < 512; ++f) acc = fmaf(x[f], wr[f], acc);
    out[idx] = fmaxf(acc, 0.f);
}

__global__ void fc2_kernel(const float* __restrict__ in, const float* __restrict__ w,
                           const float* __restrict__ b, float* __restrict__ out)
{
    int idx = blockIdx.x * blockDim.x + threadIdx.x;
    if (idx >= 64 * 50) return;
    int k = idx % 50;
    int n = idx / 50;
    const float* x  = in + n * 128;
    const float* wr = w + k * 128;
    float acc = b[k];
    for (int f = 0; f < 128; ++f) acc = fmaf(x[f], wr[f], acc);
    out[idx] = tanhf(acc);
}

__global__ void loss_kernel(const float* __restrict__ pts, float* __restrict__ out)
{
    __shared__ float acc[4][64];
    int n = threadIdx.x;
    float rx = 0.f, ry = 0.f, cx = 0.f, cy = 0.f;
    {
        const float* g = pts + n * 50;
        for (int r = 0; r < 5; ++r)
            for (int j = 0; j < 3; ++j)
                for (int d = 0; d < 2; ++d) {
                    float a0 = g[(r * 5 + j) * 2 + d];
                    float a1 = g[(r * 5 + j + 1) * 2 + d];
                    float a2 = g[(r * 5 + j + 2) * 2 + d];
                    float d0 = (a1 - a0) * (a1 - a0);
                    float d1 = (a2 - a1) * (a2 - a1);
                    float t = fmaxf(0.08f, fabsf(d1 - d0));
                    if (d == 0) rx += t; else ry += t;
                }
        for (int r = 0; r < 5; ++r)
            for (int j = 0; j < 3; ++j)
                for (int d = 0; d < 2; ++d) {
                    float a0 = g[(j * 5 + r) * 2 + d];
                    float a1 = g[((j + 1) * 5 + r) * 2 + d];
                    float a2 = g[((j + 2) * 5 + r) * 2 + d];
                    float d0 = (a1 - a0) * (a1 - a0);
                    float d1 = (a2 - a1) * (a2 - a1);
                    float t = fmaxf(0.08f, fabsf(d1 - d0));
                    if (d == 0) cx += t; else cy += t;
                }
    }
    acc[0][n] = rx; acc[1][n] = ry; acc[2][n] = cx; acc[3][n] = cy;
    __syncthreads();
    if (n == 0) {
        float s0 = 0.f, s1 = 0.f, s2 = 0.f, s3 = 0.f;
        for (int i = 0; i < 64; ++i) {
            s0 += acc[0][i]; s1 += acc[1][i]; s2 += acc[2][i]; s3 += acc[3][i];
        }
        float inv = 1.0f / (64.0f * 15.0f);
        out[3200] = s0 * inv;
        out[3201] = s1 * inv;
        out[3202] = s2 * inv;
        out[3203] = s3 * inv;
        const float* g = pts;
        float rg = 0.f, cg = 0.f;
        for (int r = 0; r < 5; ++r)
            for (int j = 0; j < 3; ++j) {
                float x0 = g[(r * 5 + j) * 2],     y0 = g[(r * 5 + j) * 2 + 1];
                float x1 = g[(r * 5 + j + 1) * 2], y1 = g[(r * 5 + j + 1) * 2 + 1];
                float x2 = g[(r * 5 + j + 2) * 2], y2 = g[(r * 5 + j + 2) * 2 + 1];
                rg += fabsf((y1 - y0) * (x1 - x2) - (y1 - y2) * (x1 - x0));
            }
        for (int r = 0; r < 5; ++r)
            for (int j = 0; j < 3; ++j) {
                float x0 = g[(j * 5 + r) * 2],       y0 = g[(j * 5 + r) * 2 + 1];
                float x1 = g[((j + 1) * 5 + r) * 2], y1 = g[((j + 1) * 5 + r) * 2 + 1];
                float x2 = g[((j + 2) * 5 + r) * 2], y2 = g[((j + 2) * 5 + r) * 2 + 1];
                cg += fabsf((y1 - y0) * (x1 - x2) - (y1 - y2) * (x1 - x0));
            }
        out[3204] = fmaxf(rg, 0.02f);
        out[3205] = fmaxf(cg, 0.02f);
    }
}

extern "C" void kernel_launch(void* const* d_in, const int* in_sizes, int n_in,
                              void* d_out, int out_size, void* d_ws, size_t ws_size,
                              hipStream_t stream)
{
    const float* x = (const float*)d_in[0];
    const float* w[8], *bia[8];
    for (int i = 0; i < 6; ++i) { w[i] = (const float*)d_in[1 + 2 * i]; bia[i] = (const float*)d_in[2 + 2 * i]; }
    w[6] = (const float*)d_in[13]; bia[6] = (const float*)d_in[14];
    w[7] = (const float*)d_in[15]; bia[7] = (const float*)d_in[16];
    const float* fc1_w = (const float*)d_in[17];
    const float* fc1_b = (const float*)d_in[18];
    const float* fc2_w = (const float*)d_in[19];
    const float* fc2_b = (const float*)d_in[20];
    float* out = (float*)d_out;

    // workspace layout (floats):
    // A:   [0 .. 6291456)      ping + sub-regions
    // Bf:  [6291456 .. 9437184) pong
    float* A      = (float*)d_ws;
    float* Bf     = A + 6291456;
    float* pooled = Bf + 3145728;
    float* fc1o   = pooled + 32768;
    float* At     = A + 2097152;   // transposed L3 output, 786432 floats
    float* pbuf   = A + 3145728;   // partials, 3145728 floats (ends exactly at Bf)

    const int N = 64;
    const float* cur = x;
    float* bufs[2] = {A, Bf};

    // ---- L0: (5,256,192) -> (8,128,96), conv+relu then norm ----
    {
        float* dst = bufs[0];
        conv42<5, 8><<<3072, 256, 0, stream>>>(cur, w[0], bia[0], dst, N, 256, 192, 8, 128, 96, 1);
        inorm_block<<<N * 8, 256, 0, stream>>>(dst, 128 * 96, 0);
        cur = dst;
    }
    // ---- L1: (8,128,96) -> (16,64,48) ----
    {
        float* dst = bufs[1];
        conv42<8, 16><<<768, 256, 0, stream>>>(cur, w[1], bia[1], dst, N, 128, 96, 16, 64, 48, 0);
        inorm_block<<<N * 16, 256, 0, stream>>>(dst, 64 * 48, 1);
        cur = dst;
    }
    // ---- L2: (16,64,48) -> (32,32,24) ----
    {
        float* dst = bufs[0];
        conv42<16, 16><<<384, 256, 0, stream>>>(cur, w[2], bia[2], dst, N, 64, 48, 32, 32, 24, 0);
        inorm_block<<<N * 32, 256, 0, stream>>>(dst, 32 * 24, 1);
        cur = dst;
    }
    // ---- L3: (32,32,24) -> (64,16,12); norm writes TRANSPOSED [c][px][n] ----
    {
        float* dst = bufs[1];
        conv42<32, 8><<<512, 192, 0, stream>>>(cur, w[3], bia[3], dst, N, 32, 24, 64, 16, 12, 0);
        inorm_wave_T<<<(N * 64 * 64 + 255) / 256, 256, 0, stream>>>(dst, At, N * 64, 64, 192, 1);
    }
    // ---- L4: (64,16,12) -> (128,8,6), lane-n + fused reduce/norm/relu ----
    {
        float* dst = bufs[0];
        conv_l4<<<256, 256, 0, stream>>>(At, w[4], pbuf);
        reduce_norm48<<<32, 256, 0, stream>>>(pbuf, dst);
        cur = dst;
    }
    // ---- L5: (128,8,6) -> (256,4,3) ----
    {
        float* dst = bufs[1];
        conv_l5<<<256, 256, 0, stream>>>(cur, w[5], pbuf);
        reduce_norm12<<<64, 256, 0, stream>>>(pbuf, dst);
        cur = dst;
    }
    // ---- L6, L7: (256,4,3) -> (256,4,3), K=3 s=1 ----
    for (int i = 6; i < 8; ++i) {
        float* dst = bufs[i & 1];
        conv_l67<<<256, 256, 0, stream>>>(cur, w[i], pbuf);
        reduce_norm12<<<64, 256, 0, stream>>>(pbuf, dst);
        cur = dst;
    }

    pool_kernel<<<(64 * 512 + 255) / 256, 256, 0, stream>>>(cur, pooled);
    fc1_kernel<<<(64 * 128 + 255) / 256, 256, 0, stream>>>(pooled, fc1_w, fc1_b, fc1o);
    fc2_kernel<<<(64 * 50 + 255) / 256, 256, 0, stream>>>(fc1o, fc2_w, fc2_b, out);
    loss_kernel<<<1, 64, 0, stream>>>(out, out);
}